// Round 1
// baseline (878.667 us; speedup 1.0000x reference)
//
#include <hip/hip_runtime.h>

#define N_NODES 10242
#define NNZ_E   71694
// rows padded to multiple of 8, +64 slack for the cooperative row over-read
#define NNZ_PAD_MAX (NNZ_E + 7 * N_NODES + 64)
#define BT      32      // B*T
#define C_IN    16
#define K_S     20
#define C_OUT   32
#define F       512     // BT * C_IN
typedef unsigned short u16;
typedef unsigned int   u32;

#define RING_ELEMS ((size_t)N_NODES * F)    // f16 elems per ring slot, layout [n][bt*16+c]
#define RING_BYTES (RING_ELEMS * 2)         // ~10.5 MB

typedef __attribute__((ext_vector_type(8)))  _Float16 half8;
typedef __attribute__((ext_vector_type(16))) float    float16;

__device__ __forceinline__ void unpack8h(uint4 u, float* f) {
    union { uint4 u; _Float16 h[8]; } v; v.u = u;
    #pragma unroll
    for (int i = 0; i < 8; ++i) f[i] = (float)v.h[i];
}
__device__ __forceinline__ uint4 pack8h(const float* f) {
    union { uint4 u; _Float16 h[8]; } v;
    #pragma unroll
    for (int i = 0; i < 8; ++i) v.h[i] = (_Float16)f[i];
    return v.u;
}
__device__ __forceinline__ u16 f2h(float f) {
    union { _Float16 h; u16 u; } v; v.h = (_Float16)f; return v.u;
}

// ---------------- single-launch CSR build + weight fragments ----------------
// One 1024-thread workgroup. cnt/cursor live in LDS (86 KB < 160 KB/CU).
// Determinism: scatter order is nondeterministic, but each row's (col,valbits)
// multiset is fixed; an in-row sort by (col, valbits) makes the final CSR —
// and hence the f32 accumulation order — fully deterministic. Rows padded to
// x8 with (col=0, val=0) entries (contribute exactly 0).

__global__ __launch_bounds__(1024) void build_kernel(
        const int* __restrict__ erow, const int* __restrict__ ecol,
        const float* __restrict__ eval, const float* __restrict__ W,
        int* __restrict__ row_ptr, int2* __restrict__ cpack,
        u16* __restrict__ wtfrag) {
    __shared__ int cnt[N_NODES];
    __shared__ int cur[N_NODES];
    __shared__ int part[1024];
    const int t = threadIdx.x;

    // B-fragments for v_mfma_f32_32x32x16_f16 (independent work, issue first):
    // lane L, reg j -> B[k=8*(L>>5)+j][col=L&31] = W[cout=col][c=k][k_cheb]
    for (int i = t; i < K_S * 64 * 8; i += 1024) {
        int j    = i & 7;
        int lane = (i >> 3) & 63;
        int k    = i >> 9;
        int cout = lane & 31;
        int c    = ((lane >> 5) << 3) + j;
        wtfrag[i] = f2h(W[cout * (C_IN * K_S) + c * K_S + k]);
    }

    for (int i = t; i < N_NODES; i += 1024) cnt[i] = 0;
    __syncthreads();
    for (int e = t; e < NNZ_E; e += 1024) atomicAdd(&cnt[erow[e]], 1);
    __syncthreads();

    // exclusive scan of padded counts (chunk-serial + Hillis-Steele over 1024)
    const int CH = (N_NODES + 1023) / 1024;   // 11
    int b0 = t * CH;
    int sloc = 0;
    for (int i = 0; i < CH; ++i) {
        int idx = b0 + i;
        if (idx < N_NODES) sloc += (cnt[idx] + 7) & ~7;
    }
    part[t] = sloc;
    __syncthreads();
    for (int off = 1; off < 1024; off <<= 1) {
        int v = (t >= off) ? part[t - off] : 0;
        __syncthreads();
        part[t] += v;
        __syncthreads();
    }
    int run = (t == 0) ? 0 : part[t - 1];
    for (int i = 0; i < CH; ++i) {
        int idx = b0 + i;
        if (idx < N_NODES) {
            cur[idx]     = run;
            row_ptr[idx] = run;
            run += (cnt[idx] + 7) & ~7;
        }
    }
    if (t == 1023) row_ptr[N_NODES] = part[1023];
    __syncthreads();

    // scatter (col, valbits) pairs directly
    for (int e = t; e < NNZ_E; e += 1024) {
        int r = erow[e];
        int p = atomicAdd(&cur[r], 1);
        cpack[p] = make_int2(ecol[e], __float_as_int(eval[e]));
    }
    __syncthreads();

    // per-row insertion sort by (col, valbits) + pad fill
    for (int r = t; r < N_NODES; r += 1024) {
        int c    = cnt[r];
        int send = cur[r];           // base + c
        int sbeg = send - c;
        for (int i = sbeg + 1; i < send; ++i) {
            int2 key = cpack[i];
            int j = i - 1;
            while (j >= sbeg) {
                int2 q = cpack[j];
                bool gt = (q.x > key.x) || (q.x == key.x && (u32)q.y > (u32)key.y);
                if (!gt) break;
                cpack[j + 1] = q;
                --j;
            }
            cpack[j + 1] = key;
        }
        int pend = sbeg + ((c + 7) & ~7);
        for (int p = send; p < pend; ++p) cpack[p] = make_int2(0, 0);
    }
}

// ---------------- transform: x (fp32) -> ring slot 0 (f16) ----------------
// ring layout: T[n][bt*16 + c]

__global__ __launch_bounds__(256) void transform_kernel(
        const float* __restrict__ x, u16* __restrict__ T0) {
    int g = blockIdx.x * 256 + threadIdx.x;   // over N*F
    int n   = g >> 9;
    int rem = g & 511;
    int bt  = rem >> 4;
    int c   = rem & 15;
    float v = x[((size_t)bt * N_NODES + n) * C_IN + c];
    T0[(size_t)n * F + rem] = f2h(v);
}

// ---------------- Chebyshev step: wave-per-node, f16 ring, fp32 math -------
// dst = alpha * L @ srcB + beta * srcA
// 256-thread blocks (4 nodes), rows padded to x8. Lane i cooperatively holds
// cpack[s+i]; v_readlane broadcasts (col, weight) into SGPRs so each 8-edge
// group issues ONE burst of 8 gathers (single global-latency round per
// typical row instead of 2+ serial cpack->gather rounds).

__global__ __launch_bounds__(256) void spmm_step_kernel(
        const u16* __restrict__ srcB, const u16* __restrict__ srcA,
        u16* __restrict__ dst,
        const int* __restrict__ row_ptr, const int2* __restrict__ cpack,
        float alpha, float beta) {
    const int lane = threadIdx.x & 63;
    const int n = (blockIdx.x << 2) + (threadIdx.x >> 6);
    if (n >= N_NODES) return;
    const int s = row_ptr[n], e_end = row_ptr[n + 1];   // padded, multiple of 8

    // hoist srcA load (independent; overlaps the row fetch)
    float a[8] = {0,0,0,0,0,0,0,0};
    if (beta != 0.f) {
        uint4 ua = ((const uint4*)(srcA + (size_t)n * F))[lane];
        unpack8h(ua, a);
    }

    int2 my = cpack[s + lane];   // padded row length <= ~24 << 64; +64 alloc slack

    float acc0[8] = {0,0,0,0,0,0,0,0};
    float acc1[8] = {0,0,0,0,0,0,0,0};

    for (int e = s; e < e_end; e += 8) {
        const int base = e - s;
        int c0 = __builtin_amdgcn_readlane(my.x, base + 0);
        int c1 = __builtin_amdgcn_readlane(my.x, base + 1);
        int c2 = __builtin_amdgcn_readlane(my.x, base + 2);
        int c3 = __builtin_amdgcn_readlane(my.x, base + 3);
        int c4 = __builtin_amdgcn_readlane(my.x, base + 4);
        int c5 = __builtin_amdgcn_readlane(my.x, base + 5);
        int c6 = __builtin_amdgcn_readlane(my.x, base + 6);
        int c7 = __builtin_amdgcn_readlane(my.x, base + 7);
        float v0 = __int_as_float(__builtin_amdgcn_readlane(my.y, base + 0));
        float v1 = __int_as_float(__builtin_amdgcn_readlane(my.y, base + 1));
        float v2 = __int_as_float(__builtin_amdgcn_readlane(my.y, base + 2));
        float v3 = __int_as_float(__builtin_amdgcn_readlane(my.y, base + 3));
        float v4 = __int_as_float(__builtin_amdgcn_readlane(my.y, base + 4));
        float v5 = __int_as_float(__builtin_amdgcn_readlane(my.y, base + 5));
        float v6 = __int_as_float(__builtin_amdgcn_readlane(my.y, base + 6));
        float v7 = __int_as_float(__builtin_amdgcn_readlane(my.y, base + 7));

        uint4 g0 = ((const uint4*)(srcB + (size_t)c0 * F))[lane];
        uint4 g1 = ((const uint4*)(srcB + (size_t)c1 * F))[lane];
        uint4 g2 = ((const uint4*)(srcB + (size_t)c2 * F))[lane];
        uint4 g3 = ((const uint4*)(srcB + (size_t)c3 * F))[lane];
        uint4 g4 = ((const uint4*)(srcB + (size_t)c4 * F))[lane];
        uint4 g5 = ((const uint4*)(srcB + (size_t)c5 * F))[lane];
        uint4 g6 = ((const uint4*)(srcB + (size_t)c6 * F))[lane];
        uint4 g7 = ((const uint4*)(srcB + (size_t)c7 * F))[lane];

        float b0[8], b1[8], b2[8], b3[8], b4[8], b5[8], b6[8], b7[8];
        unpack8h(g0, b0); unpack8h(g1, b1); unpack8h(g2, b2); unpack8h(g3, b3);
        unpack8h(g4, b4); unpack8h(g5, b5); unpack8h(g6, b6); unpack8h(g7, b7);

        #pragma unroll
        for (int i = 0; i < 8; ++i) {
            acc0[i] += v0 * b0[i];
            acc1[i] += v1 * b1[i];
            acc0[i] += v2 * b2[i];
            acc1[i] += v3 * b3[i];
            acc0[i] += v4 * b4[i];
            acc1[i] += v5 * b5[i];
            acc0[i] += v6 * b6[i];
            acc1[i] += v7 * b7[i];
        }
    }

    float y[8];
    #pragma unroll
    for (int i = 0; i < 8; ++i)
        y[i] = alpha * (acc0[i] + acc1[i]) + beta * a[i];

    ((uint4*)(dst + (size_t)n * F))[lane] = pack8h(y);
}

// ---------------- MFMA projection over a chunk (kcnt <= K_S), f16 ----------
// per wave: one node; tile M=32(bt) x N=32(cout), K=kcnt*16.
// A: m=L&31, kk=8*(L>>5)+j ; C/D: col=L&31, row=(reg&3)+8*(reg>>2)+4*(L>>5)
// (layouts harness-verified previously; C/D layout dtype-independent)

__global__ __launch_bounds__(256) void proj_mfma_kernel(
        const u16* __restrict__ ring, int R, int k0, int kcnt,
        const u16* __restrict__ wtfrag, float* __restrict__ out, int accumulate) {
    const int lane = threadIdx.x & 63;
    const int n = (blockIdx.x << 2) + (threadIdx.x >> 6);
    if (n >= N_NODES) return;
    const int col = lane & 31;
    const int grp = lane >> 5;
    const size_t aoff = (size_t)n * F + (size_t)col * 16 + grp * 8;

    union U { uint4 u; half8 h; };
    float16 acc0 = {};
    float16 acc1 = {};
    int j = 0;
    for (; j + 2 <= kcnt; j += 2) {
        int ka = k0 + j, kb = k0 + j + 1;
        U a0, b0, a1, b1;
        a0.u = *(const uint4*)(ring + (size_t)(ka % R) * RING_ELEMS + aoff);
        b0.u = *(const uint4*)(wtfrag + (size_t)ka * 512 + lane * 8);
        a1.u = *(const uint4*)(ring + (size_t)(kb % R) * RING_ELEMS + aoff);
        b1.u = *(const uint4*)(wtfrag + (size_t)kb * 512 + lane * 8);
        acc0 = __builtin_amdgcn_mfma_f32_32x32x16_f16(a0.h, b0.h, acc0, 0, 0, 0);
        acc1 = __builtin_amdgcn_mfma_f32_32x32x16_f16(a1.h, b1.h, acc1, 0, 0, 0);
    }
    if (j < kcnt) {
        int ka = k0 + j;
        U a0, b0;
        a0.u = *(const uint4*)(ring + (size_t)(ka % R) * RING_ELEMS + aoff);
        b0.u = *(const uint4*)(wtfrag + (size_t)ka * 512 + lane * 8);
        acc0 = __builtin_amdgcn_mfma_f32_32x32x16_f16(a0.h, b0.h, acc0, 0, 0, 0);
    }

    #pragma unroll
    for (int r = 0; r < 16; ++r) {
        int bt = (r & 3) + 8 * (r >> 2) + 4 * grp;
        float* op = out + ((size_t)bt * N_NODES + n) * C_OUT + col;
        float val = acc0[r] + acc1[r];
        if (accumulate) *op += val;
        else            *op  = val;
    }
}

// ---------------- host launch ----------------

extern "C" void kernel_launch(void* const* d_in, const int* in_sizes, int n_in,
                              void* d_out, int out_size, void* d_ws, size_t ws_size,
                              hipStream_t stream) {
    const float* x    = (const float*)d_in[0];
    const int*   erow = (const int*)  d_in[1];
    const int*   ecol = (const int*)  d_in[2];
    const float* eval = (const float*)d_in[3];
    const float* W    = (const float*)d_in[4];
    float* out = (float*)d_out;

    char* ws = (char*)d_ws;
    size_t o = 0;
    auto alloc = [&](size_t bytes) -> char* {
        o = (o + 511) & ~(size_t)511;
        char* r = ws + o;
        o += bytes;
        return r;
    };
    int*   row_ptr = (int*)  alloc((size_t)(N_NODES + 1) * 4);
    int2*  cpack   = (int2*) alloc((size_t)NNZ_PAD_MAX * 8);
    u16*   wtfrag  = (u16*)  alloc((size_t)K_S * 512 * 2);

    // ring gets everything that's left; R = 20 (~210 MB) -> single proj pass,
    // gracefully degrades to chunked passes on smaller workspaces.
    o = (o + 511) & ~(size_t)511;
    int R = (int)((ws_size - o) / RING_BYTES);
    if (R > K_S) R = K_S;
    if (R < 3)  R = 3;
    u16* ring = (u16*)(ws + o);
    auto slot = [&](int k) -> u16* { return ring + (size_t)(k % R) * RING_ELEMS; };

    build_kernel<<<1, 1024, 0, stream>>>(erow, ecol, eval, W, row_ptr, cpack, wtfrag);

    const int grid4 = (N_NODES + 3) / 4;
    int c0 = 0;
    auto maybe_pass = [&](int k_done) {
        int target = K_S - c0;
        if (target > R) target = R;   // chunk == R safe (stream-ordered)
        if (target > 0 && (k_done - c0 + 1) == target) {
            proj_mfma_kernel<<<grid4, 256, 0, stream>>>(
                ring, R, c0, target, wtfrag, out, (c0 > 0) ? 1 : 0);
            c0 += target;
        }
    };

    // T0 -> slot 0
    transform_kernel<<<(int)(RING_ELEMS / 256), 256, 0, stream>>>(x, slot(0));
    maybe_pass(0);

    // T1 = L T0 ; Tk = 2 L T_{k-1} - T_{k-2}
    for (int k = 1; k < K_S; ++k) {
        const u16* srcB = slot(k - 1);
        const u16* srcA = (k >= 2) ? slot(k - 2) : slot(k - 1);  // unread when beta==0
        float alpha = (k == 1) ? 1.f : 2.f;
        float beta  = (k == 1) ? 0.f : -1.f;
        spmm_step_kernel<<<grid4, 256, 0, stream>>>(
            srcB, srcA, slot(k), row_ptr, cpack, alpha, beta);
        maybe_pass(k);
    }
}

// Round 2
// 456.451 us; speedup vs baseline: 1.9250x; 1.9250x over previous
//
#include <hip/hip_runtime.h>

#define N_NODES 10242
#define NNZ_E   71694
// rows padded to multiple of 8, +64 slack for the cooperative row over-read
#define NNZ_PAD_MAX (NNZ_E + 7 * N_NODES + 64)
#define BT      32      // B*T
#define C_IN    16
#define K_S     20
#define C_OUT   32
#define F       512     // BT * C_IN
typedef unsigned short u16;
typedef unsigned int   u32;

#define RING_ELEMS ((size_t)N_NODES * F)    // f16 elems per ring slot, layout [n][bt*16+c]
#define RING_BYTES (RING_ELEMS * 2)         // ~10.5 MB

typedef __attribute__((ext_vector_type(8)))  _Float16 half8;
typedef __attribute__((ext_vector_type(16))) float    float16;

__device__ __forceinline__ void unpack8h(uint4 u, float* f) {
    union { uint4 u; _Float16 h[8]; } v; v.u = u;
    #pragma unroll
    for (int i = 0; i < 8; ++i) f[i] = (float)v.h[i];
}
__device__ __forceinline__ uint4 pack8h(const float* f) {
    union { uint4 u; _Float16 h[8]; } v;
    #pragma unroll
    for (int i = 0; i < 8; ++i) v.h[i] = (_Float16)f[i];
    return v.u;
}
__device__ __forceinline__ u16 f2h(float f) {
    union { _Float16 h; u16 u; } v; v.h = (_Float16)f; return v.u;
}

// ---------------- parallel CSR build (5 small wide-grid kernels) -----------
// Determinism: scatter order is nondeterministic, but each row's (col,valbits)
// multiset is fixed; an in-row sort by (col, valbits) makes the final CSR —
// and hence the f32 accumulation order — fully deterministic. Rows padded to
// x8 with (col=0, val=0) entries (contribute exactly 0).

// zero cnt + build W fragments (independent work, one launch)
// B-fragments for v_mfma_f32_32x32x16_f16:
// lane L, reg j -> B[k=8*(L>>5)+j][col=L&31] = W[cout=col][c=k][k_cheb]
__global__ __launch_bounds__(256) void init_kernel(
        const float* __restrict__ W, int* __restrict__ cnt,
        u16* __restrict__ wtfrag) {
    int i = blockIdx.x * 256 + threadIdx.x;
    if (i < N_NODES) cnt[i] = 0;
    int w = i - N_NODES;
    if (w >= 0 && w < K_S * 64 * 8) {
        int j    = w & 7;
        int lane = (w >> 3) & 63;
        int k    = w >> 9;
        int cout = lane & 31;
        int c    = ((lane >> 5) << 3) + j;
        wtfrag[w] = f2h(W[cout * (C_IN * K_S) + c * K_S + k]);
    }
}

__global__ __launch_bounds__(256) void count_kernel(
        const int* __restrict__ erow, int* cnt) {
    int e = blockIdx.x * 256 + threadIdx.x;
    if (e < NNZ_E) atomicAdd(&cnt[erow[e]], 1);
}

// exclusive scan of x8-padded counts; single 256-thread block (tiny: ~10k adds)
__global__ __launch_bounds__(256) void scan_kernel(
        const int* __restrict__ cnt, int* row_ptr, int* cursor) {
    const int T = 256;
    const int chunk = (N_NODES + T - 1) / T;  // 41
    __shared__ int part[T];
    int t = threadIdx.x;
    int base = t * chunk;
    int s = 0;
    for (int i = 0; i < chunk; ++i) {
        int idx = base + i;
        if (idx < N_NODES) s += (cnt[idx] + 7) & ~7;
    }
    part[t] = s;
    __syncthreads();
    for (int off = 1; off < T; off <<= 1) {
        int v = (t >= off) ? part[t - off] : 0;
        __syncthreads();
        part[t] += v;
        __syncthreads();
    }
    int run = (t == 0) ? 0 : part[t - 1];
    for (int i = 0; i < chunk; ++i) {
        int idx = base + i;
        if (idx < N_NODES) {
            row_ptr[idx] = run;
            cursor[idx]  = run;
            run += (cnt[idx] + 7) & ~7;
        }
    }
    if (t == T - 1) row_ptr[N_NODES] = part[T - 1];
}

// scatter (col, valbits) pairs directly into cpack (no eidx indirection)
__global__ __launch_bounds__(256) void scatter_kernel(
        const int* __restrict__ erow, const int* __restrict__ ecol,
        const float* __restrict__ eval, int* cursor, int2* __restrict__ cpack) {
    int e = blockIdx.x * 256 + threadIdx.x;
    if (e < NNZ_E) {
        int p = atomicAdd(&cursor[erow[e]], 1);
        cpack[p] = make_int2(ecol[e], __float_as_int(eval[e]));
    }
}

// per-row insertion sort by (col, valbits) + x8 pad fill; one thread per row
__global__ __launch_bounds__(256) void finalize_kernel(
        const int* __restrict__ row_ptr, const int* __restrict__ cursor,
        int2* cpack) {
    int r = blockIdx.x * 256 + threadIdx.x;
    if (r >= N_NODES) return;
    int sbeg = row_ptr[r];
    int send = cursor[r];        // sbeg + real count
    int pend = row_ptr[r + 1];   // sbeg + padded count
    for (int i = sbeg + 1; i < send; ++i) {
        int2 key = cpack[i];
        int j = i - 1;
        while (j >= sbeg) {
            int2 q = cpack[j];
            bool gt = (q.x > key.x) || (q.x == key.x && (u32)q.y > (u32)key.y);
            if (!gt) break;
            cpack[j + 1] = q;
            --j;
        }
        cpack[j + 1] = key;
    }
    for (int p = send; p < pend; ++p) cpack[p] = make_int2(0, 0);
}

// ---------------- transform: x (fp32) -> ring slot 0 (f16) ----------------
// ring layout: T[n][bt*16 + c]

__global__ __launch_bounds__(256) void transform_kernel(
        const float* __restrict__ x, u16* __restrict__ T0) {
    int g = blockIdx.x * 256 + threadIdx.x;   // over N*F
    int n   = g >> 9;
    int rem = g & 511;
    int bt  = rem >> 4;
    int c   = rem & 15;
    float v = x[((size_t)bt * N_NODES + n) * C_IN + c];
    T0[(size_t)n * F + rem] = f2h(v);
}

// ---------------- Chebyshev step: wave-per-node, f16 ring, fp32 math -------
// dst = alpha * L @ srcB + beta * srcA
// 256-thread blocks (4 nodes), rows padded to x8. Lane i cooperatively holds
// cpack[s+i]; v_readlane broadcasts (col, weight) into SGPRs so each 8-edge
// group issues ONE burst of 8 gathers (single global-latency round per
// typical row instead of 2+ serial cpack->gather rounds).

__global__ __launch_bounds__(256) void spmm_step_kernel(
        const u16* __restrict__ srcB, const u16* __restrict__ srcA,
        u16* __restrict__ dst,
        const int* __restrict__ row_ptr, const int2* __restrict__ cpack,
        float alpha, float beta) {
    const int lane = threadIdx.x & 63;
    const int n = (blockIdx.x << 2) + (threadIdx.x >> 6);
    if (n >= N_NODES) return;
    const int s = row_ptr[n], e_end = row_ptr[n + 1];   // padded, multiple of 8

    // hoist srcA load (independent; overlaps the row fetch)
    float a[8] = {0,0,0,0,0,0,0,0};
    if (beta != 0.f) {
        uint4 ua = ((const uint4*)(srcA + (size_t)n * F))[lane];
        unpack8h(ua, a);
    }

    int2 my = cpack[s + lane];   // padded row length <= ~24 << 64; +64 alloc slack

    float acc0[8] = {0,0,0,0,0,0,0,0};
    float acc1[8] = {0,0,0,0,0,0,0,0};

    for (int e = s; e < e_end; e += 8) {
        const int base = e - s;
        int c0 = __builtin_amdgcn_readlane(my.x, base + 0);
        int c1 = __builtin_amdgcn_readlane(my.x, base + 1);
        int c2 = __builtin_amdgcn_readlane(my.x, base + 2);
        int c3 = __builtin_amdgcn_readlane(my.x, base + 3);
        int c4 = __builtin_amdgcn_readlane(my.x, base + 4);
        int c5 = __builtin_amdgcn_readlane(my.x, base + 5);
        int c6 = __builtin_amdgcn_readlane(my.x, base + 6);
        int c7 = __builtin_amdgcn_readlane(my.x, base + 7);
        float v0 = __int_as_float(__builtin_amdgcn_readlane(my.y, base + 0));
        float v1 = __int_as_float(__builtin_amdgcn_readlane(my.y, base + 1));
        float v2 = __int_as_float(__builtin_amdgcn_readlane(my.y, base + 2));
        float v3 = __int_as_float(__builtin_amdgcn_readlane(my.y, base + 3));
        float v4 = __int_as_float(__builtin_amdgcn_readlane(my.y, base + 4));
        float v5 = __int_as_float(__builtin_amdgcn_readlane(my.y, base + 5));
        float v6 = __int_as_float(__builtin_amdgcn_readlane(my.y, base + 6));
        float v7 = __int_as_float(__builtin_amdgcn_readlane(my.y, base + 7));

        uint4 g0 = ((const uint4*)(srcB + (size_t)c0 * F))[lane];
        uint4 g1 = ((const uint4*)(srcB + (size_t)c1 * F))[lane];
        uint4 g2 = ((const uint4*)(srcB + (size_t)c2 * F))[lane];
        uint4 g3 = ((const uint4*)(srcB + (size_t)c3 * F))[lane];
        uint4 g4 = ((const uint4*)(srcB + (size_t)c4 * F))[lane];
        uint4 g5 = ((const uint4*)(srcB + (size_t)c5 * F))[lane];
        uint4 g6 = ((const uint4*)(srcB + (size_t)c6 * F))[lane];
        uint4 g7 = ((const uint4*)(srcB + (size_t)c7 * F))[lane];

        float b0[8], b1[8], b2[8], b3[8], b4[8], b5[8], b6[8], b7[8];
        unpack8h(g0, b0); unpack8h(g1, b1); unpack8h(g2, b2); unpack8h(g3, b3);
        unpack8h(g4, b4); unpack8h(g5, b5); unpack8h(g6, b6); unpack8h(g7, b7);

        #pragma unroll
        for (int i = 0; i < 8; ++i) {
            acc0[i] += v0 * b0[i];
            acc1[i] += v1 * b1[i];
            acc0[i] += v2 * b2[i];
            acc1[i] += v3 * b3[i];
            acc0[i] += v4 * b4[i];
            acc1[i] += v5 * b5[i];
            acc0[i] += v6 * b6[i];
            acc1[i] += v7 * b7[i];
        }
    }

    float y[8];
    #pragma unroll
    for (int i = 0; i < 8; ++i)
        y[i] = alpha * (acc0[i] + acc1[i]) + beta * a[i];

    ((uint4*)(dst + (size_t)n * F))[lane] = pack8h(y);
}

// ---------------- MFMA projection over a chunk (kcnt <= K_S), f16 ----------
// per wave: one node; tile M=32(bt) x N=32(cout), K=kcnt*16.
// A: m=L&31, kk=8*(L>>5)+j ; C/D: col=L&31, row=(reg&3)+8*(reg>>2)+4*(L>>5)
// (layouts harness-verified previously; C/D layout dtype-independent)

__global__ __launch_bounds__(256) void proj_mfma_kernel(
        const u16* __restrict__ ring, int R, int k0, int kcnt,
        const u16* __restrict__ wtfrag, float* __restrict__ out, int accumulate) {
    const int lane = threadIdx.x & 63;
    const int n = (blockIdx.x << 2) + (threadIdx.x >> 6);
    if (n >= N_NODES) return;
    const int col = lane & 31;
    const int grp = lane >> 5;
    const size_t aoff = (size_t)n * F + (size_t)col * 16 + grp * 8;

    union U { uint4 u; half8 h; };
    float16 acc0 = {};
    float16 acc1 = {};
    int j = 0;
    for (; j + 2 <= kcnt; j += 2) {
        int ka = k0 + j, kb = k0 + j + 1;
        U a0, b0, a1, b1;
        a0.u = *(const uint4*)(ring + (size_t)(ka % R) * RING_ELEMS + aoff);
        b0.u = *(const uint4*)(wtfrag + (size_t)ka * 512 + lane * 8);
        a1.u = *(const uint4*)(ring + (size_t)(kb % R) * RING_ELEMS + aoff);
        b1.u = *(const uint4*)(wtfrag + (size_t)kb * 512 + lane * 8);
        acc0 = __builtin_amdgcn_mfma_f32_32x32x16_f16(a0.h, b0.h, acc0, 0, 0, 0);
        acc1 = __builtin_amdgcn_mfma_f32_32x32x16_f16(a1.h, b1.h, acc1, 0, 0, 0);
    }
    if (j < kcnt) {
        int ka = k0 + j;
        U a0, b0;
        a0.u = *(const uint4*)(ring + (size_t)(ka % R) * RING_ELEMS + aoff);
        b0.u = *(const uint4*)(wtfrag + (size_t)ka * 512 + lane * 8);
        acc0 = __builtin_amdgcn_mfma_f32_32x32x16_f16(a0.h, b0.h, acc0, 0, 0, 0);
    }

    #pragma unroll
    for (int r = 0; r < 16; ++r) {
        int bt = (r & 3) + 8 * (r >> 2) + 4 * grp;
        float* op = out + ((size_t)bt * N_NODES + n) * C_OUT + col;
        float val = acc0[r] + acc1[r];
        if (accumulate) *op += val;
        else            *op  = val;
    }
}

// ---------------- host launch ----------------

extern "C" void kernel_launch(void* const* d_in, const int* in_sizes, int n_in,
                              void* d_out, int out_size, void* d_ws, size_t ws_size,
                              hipStream_t stream) {
    const float* x    = (const float*)d_in[0];
    const int*   erow = (const int*)  d_in[1];
    const int*   ecol = (const int*)  d_in[2];
    const float* eval = (const float*)d_in[3];
    const float* W    = (const float*)d_in[4];
    float* out = (float*)d_out;

    char* ws = (char*)d_ws;
    size_t o = 0;
    auto alloc = [&](size_t bytes) -> char* {
        o = (o + 511) & ~(size_t)511;
        char* r = ws + o;
        o += bytes;
        return r;
    };
    int*   cnt     = (int*)  alloc((size_t)N_NODES * 4);
    int*   row_ptr = (int*)  alloc((size_t)(N_NODES + 1) * 4);
    int*   cursor  = (int*)  alloc((size_t)N_NODES * 4);
    int2*  cpack   = (int2*) alloc((size_t)NNZ_PAD_MAX * 8);
    u16*   wtfrag  = (u16*)  alloc((size_t)K_S * 512 * 2);

    // ring gets everything that's left; R = 20 (~210 MB) -> single proj pass,
    // gracefully degrades to chunked passes on smaller workspaces.
    o = (o + 511) & ~(size_t)511;
    int R = (int)((ws_size - o) / RING_BYTES);
    if (R > K_S) R = K_S;
    if (R < 3)  R = 3;
    u16* ring = (u16*)(ws + o);
    auto slot = [&](int k) -> u16* { return ring + (size_t)(k % R) * RING_ELEMS; };

    // CSR build: 5 parallel kernels (no eidx, no cpack megafill)
    init_kernel<<<(N_NODES + K_S * 512 + 255) / 256, 256, 0, stream>>>(W, cnt, wtfrag);
    count_kernel<<<(NNZ_E + 255) / 256, 256, 0, stream>>>(erow, cnt);
    scan_kernel<<<1, 256, 0, stream>>>(cnt, row_ptr, cursor);
    scatter_kernel<<<(NNZ_E + 255) / 256, 256, 0, stream>>>(erow, ecol, eval, cursor, cpack);
    finalize_kernel<<<(N_NODES + 255) / 256, 256, 0, stream>>>(row_ptr, cursor, cpack);

    const int grid4 = (N_NODES + 3) / 4;
    int c0 = 0;
    auto maybe_pass = [&](int k_done) {
        int target = K_S - c0;
        if (target > R) target = R;   // chunk == R safe (stream-ordered)
        if (target > 0 && (k_done - c0 + 1) == target) {
            proj_mfma_kernel<<<grid4, 256, 0, stream>>>(
                ring, R, c0, target, wtfrag, out, (c0 > 0) ? 1 : 0);
            c0 += target;
        }
    };

    // T0 -> slot 0
    transform_kernel<<<(int)(RING_ELEMS / 256), 256, 0, stream>>>(x, slot(0));
    maybe_pass(0);

    // T1 = L T0 ; Tk = 2 L T_{k-1} - T_{k-2}
    for (int k = 1; k < K_S; ++k) {
        const u16* srcB = slot(k - 1);
        const u16* srcA = (k >= 2) ? slot(k - 2) : slot(k - 1);  // unread when beta==0
        float alpha = (k == 1) ? 1.f : 2.f;
        float beta  = (k == 1) ? 0.f : -1.f;
        spmm_step_kernel<<<grid4, 256, 0, stream>>>(
            srcB, srcA, slot(k), row_ptr, cpack, alpha, beta);
        maybe_pass(k);
    }
}